// Round 3
// baseline (671.742 us; speedup 1.0000x reference)
//
#include <hip/hip_runtime.h>
#include <hip/hip_bf16.h>
#include <math.h>

// FlexBertGLUMoE: S=8192 tokens, H=1024, E=8, K=2, F=2048, C=2560
#define S_TOK 8192
#define HDIM  1024
#define FDIM  2048
#define CAP   2560

typedef unsigned short u16;
typedef short  s16x8 __attribute__((ext_vector_type(8)));   // 8 bf16 in 4 VGPRs
typedef float  f32x4 __attribute__((ext_vector_type(4)));

__device__ __forceinline__ u16 f2b(float f){
  unsigned u = __builtin_bit_cast(unsigned, f);
  u = (u + 0x7FFFu + ((u >> 16) & 1u)) >> 16;   // RNE
  return (u16)u;
}
__device__ __forceinline__ float b2f(u16 h){
  unsigned u = ((unsigned)h) << 16;
  return __builtin_bit_cast(float, u);
}
__device__ __forceinline__ void gl_lds16(const u16* g, u16* l){
  // async global->LDS, 16B per lane; LDS dest = wave-uniform base + lane*16
  auto gp = (const __attribute__((address_space(1))) unsigned int*)g;
  auto lp = (__attribute__((address_space(3))) unsigned int*)l;
  __builtin_amdgcn_global_load_lds(gp, lp, 16, 0, 0);
}
// tanh-GELU: max |delta| vs exact erf-GELU ~3e-4, invisible under bf16 rounding
__device__ __forceinline__ float gelu_t(float a){
  float z = 0.7978845608f * a * (1.f + 0.044715f * a * a);
  float e = __expf(-2.f * fabsf(z));
  float th = (1.f - e) / (1.f + e);
  th = (z < 0.f) ? -th : th;
  return 0.5f * a * (1.f + th);
}

// GLU column reorder: W_in col c (0..4095) -> WiT row. Blocks of 64 rows =
// [32 a-cols | 32 g-cols] so each GEMM1 wave owns matching a/g fragments.
__device__ __forceinline__ int glu_reorder(int c){
  int h = (c >= 2048) ? 1 : 0;
  int cc = c - (h << 11);
  return ((cc >> 5) << 6) + (h << 5) + (cc & 31);
}

// ---------------- weight transpose + bf16 cast: [E][R][C] f32 -> [E][C][R] bf16
template<int REORDER>
__global__ __launch_bounds__(256) void k_transpose(const float* __restrict__ in,
                                                   u16* __restrict__ out, int R, int Cc){
  __shared__ float tile[32][33];
  int e = blockIdx.z;
  const float* ip = in + (size_t)e * R * Cc;
  u16* op = out + (size_t)e * R * Cc;
  int c0 = blockIdx.x * 32, r0 = blockIdx.y * 32;
  int tx = threadIdx.x, ty = threadIdx.y;
  #pragma unroll
  for (int j = 0; j < 32; j += 8)
    tile[ty + j][tx] = ip[(size_t)(r0 + ty + j) * Cc + c0 + tx];
  __syncthreads();
  #pragma unroll
  for (int j = 0; j < 32; j += 8){
    int c = c0 + ty + j;
    int rp = REORDER ? glu_reorder(c) : c;
    op[(size_t)rp * R + r0 + tx] = f2b(tile[tx][ty + j]);
  }
}

// ---------------- gating: fp64 logits (ranking must match np ref), softmax, top-2
__global__ __launch_bounds__(256) void k_gating(const float* __restrict__ x,
                                                const float* __restrict__ Wg,
                                                int* __restrict__ eidx, float* __restrict__ vals){
  __shared__ float wgT[8][1024];
  int t = threadIdx.x;
  for (int i = t; i < 8192; i += 256) wgT[i & 7][i >> 3] = Wg[i];
  __syncthreads();
  int wid = t >> 6, l = t & 63;
  int s = blockIdx.x * 4 + wid;
  const float* xr = x + (size_t)s * HDIM;
  double acc[8] = {0,0,0,0,0,0,0,0};
  for (int j = 0; j < 16; j++){
    int h = l + 64 * j;
    float xv = xr[h];
    #pragma unroll
    for (int e = 0; e < 8; e++) acc[e] += (double)xv * (double)wgT[e][h];
  }
  #pragma unroll
  for (int off = 32; off; off >>= 1)
    #pragma unroll
    for (int e = 0; e < 8; e++) acc[e] += __shfl_down(acc[e], off);
  if (l == 0){
    double mx = acc[0];
    #pragma unroll
    for (int e = 1; e < 8; e++) mx = acc[e] > mx ? acc[e] : mx;
    double ex[8], sum = 0.0;
    #pragma unroll
    for (int e = 0; e < 8; e++){ ex[e] = exp(acc[e] - mx); sum += ex[e]; }
    double inv = 1.0 / sum;
    double p0 = -1.0; int e0 = 0;
    #pragma unroll
    for (int e = 0; e < 8; e++){ double p = ex[e] * inv; if (p > p0){ p0 = p; e0 = e; } }
    double p1 = -1.0; int e1 = 0;
    #pragma unroll
    for (int e = 0; e < 8; e++){ double p = ex[e] * inv; if (e != e0 && p > p1){ p1 = p; e1 = e; } }
    eidx[s] = e0;          vals[s] = (float)p0;
    eidx[S_TOK + s] = e1;  vals[S_TOK + s] = (float)p1;
  }
}

// ---------------- capacity scan (flat order i = k*S + s), slots, gates, counts, rev map
__global__ __launch_bounds__(1024) void k_scan(const int* __restrict__ eidx,
                                               const float* __restrict__ vals,
                                               int* __restrict__ slot, float* __restrict__ gates,
                                               int* __restrict__ cnt, int* __restrict__ rev){
  __shared__ int sc[1024][8];
  __shared__ unsigned char keepb[2 * S_TOK];
  int t = threadIdx.x;
  int le[16];
  int c[8] = {0,0,0,0,0,0,0,0};
  #pragma unroll
  for (int j = 0; j < 16; j++){ int e = eidx[t * 16 + j]; le[j] = e; c[e]++; }
  #pragma unroll
  for (int e = 0; e < 8; e++) sc[t][e] = c[e];
  __syncthreads();
  for (int st = 1; st < 1024; st <<= 1){
    int tmp[8] = {0,0,0,0,0,0,0,0};
    bool act = (t >= st);
    if (act){
      #pragma unroll
      for (int e = 0; e < 8; e++) tmp[e] = sc[t - st][e];
    }
    __syncthreads();
    if (act){
      #pragma unroll
      for (int e = 0; e < 8; e++) sc[t][e] += tmp[e];
    }
    __syncthreads();
  }
  int run[8];
  #pragma unroll
  for (int e = 0; e < 8; e++) run[e] = t ? sc[t - 1][e] : 0;
  #pragma unroll
  for (int j = 0; j < 16; j++){
    int i = t * 16 + j; int e = le[j]; int loc = run[e]++;
    int kp = (loc < CAP);
    keepb[i] = (unsigned char)kp;
    int sl = kp ? (e * CAP + loc) : -1;
    slot[i] = sl;
    if (kp) rev[sl] = i;
  }
  if (t < 8) cnt[t] = min(sc[1023][t], CAP);
  __syncthreads();
  #pragma unroll
  for (int r = 0; r < 8; r++){
    int s = t + 1024 * r;
    float g0 = keepb[s]         ? vals[s]         : 0.f;
    float g1 = keepb[S_TOK + s] ? vals[S_TOK + s] : 0.f;
    float inv = 1.f / fmaxf(g0 + g1, 1e-9f);
    gates[s] = g0 * inv;
    gates[S_TOK + s] = g1 * inv;
  }
}

// ---------------- scatter kept tokens into expert buffers (f32 -> bf16)
__global__ __launch_bounds__(256) void k_scatter(const float* __restrict__ x,
                                                 const int* __restrict__ slot,
                                                 u16* __restrict__ A){
  int i = blockIdx.x;
  int sl = slot[i];
  if (sl < 0) return;
  int s = i & (S_TOK - 1);
  int t = threadIdx.x;
  float4 v = ((const float4*)(x + (size_t)s * HDIM))[t];
  ushort4 o; o.x = f2b(v.x); o.y = f2b(v.y); o.z = f2b(v.z); o.w = f2b(v.w);
  ((ushort4*)(A + (size_t)sl * HDIM))[t] = o;
}

// ================= 256x256 8-phase GEMM (T1+T2+T3+T4+T5) =================
// A [E][CAP][LDK] bf16 row-major, B [E][NB][LDK] bf16 (N-major), BK=64.
// 8 waves as 2M x 4N; per-wave output 128x64. LDS 128KB: A/B x 2 halves x dbuf.
// T2: LDS[row][col] holds global[row][col ^ ((row&7)*8)] (u16 units) --
// linear global_load_lds dest + inverse-swizzled source + swizzled ds_read.
// T1: bijective XCD chunk remap (nwg % 8 == 0) -> each XCD works one expert,
// consecutive blocks share the B-tile (L2-resident).

#define STAGE_A(h, tt, par) { \
    const u16* gp_ = Ap + (size_t)((h)*128 + c0*8) * LDK + (size_t)(tt) * 64 + srow_off; \
    u16* lp_ = lds + (par)*16384 + (h)*8192 + c0*512; \
    gl_lds16(gp_, lp_); gl_lds16(gp_ + (size_t)8*LDK, lp_ + 512); }

#define STAGE_B(h, tt, par) { \
    const u16* gp_ = Bp + (size_t)((h)*128 + c0*8) * LDK + (size_t)(tt) * 64 + srow_off; \
    u16* lp_ = lds + 32768 + (par)*16384 + (h)*8192 + c0*512; \
    gl_lds16(gp_, lp_); gl_lds16(gp_ + (size_t)8*LDK, lp_ + 512); }

#define PH(P, KSW, NH, STAGE_CODE, POST_CODE) { \
    __builtin_amdgcn_sched_barrier(0); \
    if ((NH) == 0) { \
      _Pragma("unroll") \
      for (int m_ = 0; m_ < 8; ++m_) \
        af[m_] = *(const s16x8*)&lds[(P)*16384 + aoff + m_*1024 + (KSW)]; \
    } \
    bf[0] = *(const s16x8*)&lds[32768 + (P)*16384 + boff + (2*(NH))*1024 + (KSW)]; \
    bf[1] = *(const s16x8*)&lds[32768 + (P)*16384 + boff + (2*(NH)+1)*1024 + (KSW)]; \
    STAGE_CODE \
    __builtin_amdgcn_sched_barrier(0); __builtin_amdgcn_s_barrier(); \
    asm volatile("s_waitcnt lgkmcnt(0)" ::: "memory"); \
    __builtin_amdgcn_sched_barrier(0); \
    __builtin_amdgcn_s_setprio(1); \
    _Pragma("unroll") \
    for (int m_ = 0; m_ < 8; ++m_){ \
      acc[m_][2*(NH)]   = __builtin_amdgcn_mfma_f32_16x16x32_bf16(af[m_], bf[0], acc[m_][2*(NH)],   0, 0, 0); \
      acc[m_][2*(NH)+1] = __builtin_amdgcn_mfma_f32_16x16x32_bf16(af[m_], bf[1], acc[m_][2*(NH)+1], 0, 0, 0); \
    } \
    __builtin_amdgcn_s_setprio(0); \
    POST_CODE \
    __builtin_amdgcn_sched_barrier(0); __builtin_amdgcn_s_barrier(); }

template<int NK, int LDK, int NB, int IS_GLU, int FUSE>
__global__ __launch_bounds__(512, 2) void k_gemm8(const u16* __restrict__ Aall,
                                                  const u16* __restrict__ Ball,
                                                  u16* __restrict__ Out,
                                                  float* __restrict__ yout,
                                                  const int* __restrict__ cnt,
                                                  const int* __restrict__ rev,
                                                  const float* __restrict__ gates){
  // T1: bijective chunked XCD remap of the flattened block id (nwg % 8 == 0)
  const int gx = gridDim.x, gy = gridDim.y;
  const int o = blockIdx.x + gx * (blockIdx.y + gy * blockIdx.z);
  const int nwg = gx * gy * (int)gridDim.z;
  const int q = nwg >> 3;
  const int w = (o & 7) * q + (o >> 3);
  const int mt = w % gx;
  const int t1 = w / gx;
  const int nt = t1 % gy;
  const int e  = t1 / gy;
  if (mt * 256 >= cnt[e]) return;
  __shared__ __align__(1024) u16 lds[65536];   // 128 KiB
  const u16* Ap = Aall + (size_t)e * CAP * LDK + (size_t)mt * 256 * LDK;
  const u16* Bp = Ball + (size_t)e * NB * LDK + (size_t)nt * 256 * LDK;

  const int t = threadIdx.x, wid = t >> 6, l = t & 63;
  const int wm = wid >> 2, wn = wid & 3;
  const int lrow = l & 15, lkhi = l >> 4;
  const int c0 = wid * 2;                      // this wave's 2 staging chunks
  // staging per-lane: row (l>>3) of the 8-row chunk, col pre-inverse-swizzled
  const size_t srow_off = (size_t)(l >> 3) * LDK + (size_t)(((l & 7) * 8) ^ ((l >> 3) * 8));
  // fragment read bases (u16 indices, excluding buffer-parity term)
  const int aoff = wm * 8192 + lrow * 64;
  const int boff = (wn >> 1) * 8192 + ((wn & 1) * 64 + lrow) * 64;
  const int sx   = (l & 7) * 8;                // == (row&7)*8 for all frag reads
  const int ksw0 = (lkhi * 8) ^ sx;            // kk=0 swizzled k-offset
  const int ksw1 = (32 + lkhi * 8) ^ sx;       // kk=1

  f32x4 acc[8][4] = {};
  s16x8 af[8], bf[2];

  // prologue: tile0 (A0,A1,B0,B1 -> buf0), tile1 A-halves -> buf1
  STAGE_A(0, 0, 0) STAGE_A(1, 0, 0) STAGE_B(0, 0, 0) STAGE_B(1, 0, 0)
  STAGE_A(0, 1, 1) STAGE_A(1, 1, 1)
  asm volatile("s_waitcnt vmcnt(4)" ::: "memory");
  __builtin_amdgcn_sched_barrier(0); __builtin_amdgcn_s_barrier();

  #pragma unroll 1
  for (int t2 = 0; t2 < NK / 2; ++t2){
    const int te = 2 * t2;
    const bool nl = (t2 < NK / 2 - 1);
    // ---- tile te (buf 0) ----
    PH(0, ksw0, 0, { STAGE_B(0, te + 1, 1) }, {})
    PH(0, ksw0, 1, { STAGE_B(1, te + 1, 1) }, {})
    PH(0, ksw1, 0, {}, {})
    PH(0, ksw1, 1,
       { if (nl){ STAGE_A(0, te + 2, 0) STAGE_A(1, te + 2, 0) } },
       { if (nl){ asm volatile("s_waitcnt vmcnt(4)" ::: "memory"); }
         else   { asm volatile("s_waitcnt vmcnt(0)" ::: "memory"); } })
    // ---- tile te+1 (buf 1) ----
    PH(1, ksw0, 0, { if (nl){ STAGE_B(0, te + 2, 0) } }, {})
    PH(1, ksw0, 1, { if (nl){ STAGE_B(1, te + 2, 0) } }, {})
    PH(1, ksw1, 0, {}, {})
    PH(1, ksw1, 1,
       { if (nl){ STAGE_A(0, te + 3, 1) STAGE_A(1, te + 3, 1) } },
       { if (nl){ asm volatile("s_waitcnt vmcnt(4)" ::: "memory"); } })
  }

  // epilogue
  const int rowb = mt * 256 + wm * 128 + lkhi * 4;
  if (IS_GLU){
    u16* hp = Out + (size_t)e * CAP * FDIM;
    const int colb = (nt * 4 + wn) * 32 + lrow;
    #pragma unroll
    for (int m = 0; m < 8; ++m)
      #pragma unroll
      for (int np = 0; np < 2; ++np)
        #pragma unroll
        for (int r = 0; r < 4; ++r){
          size_t row = (size_t)(rowb + m * 16 + r);
          float a = acc[m][np][r], g = acc[m][np + 2][r];
          hp[row * FDIM + colb + np * 16] = f2b(gelu_t(a) * g);
        }
  } else if (FUSE){
    // fused gather: y[token] += gate * acc  (f32 atomics, device scope)
    const int cE = cnt[e];
    const int colb = nt * 256 + wn * 64 + lrow;
    #pragma unroll
    for (int m = 0; m < 8; ++m)
      #pragma unroll
      for (int r = 0; r < 4; ++r){
        int row = rowb + m * 16 + r;
        if (row < cE){
          int i = rev[e * CAP + row];
          float g = gates[i];
          int s = i & (S_TOK - 1);
          float* yp = yout + (size_t)s * HDIM + colb;
          #pragma unroll
          for (int n = 0; n < 4; ++n)
            atomicAdd(yp + n * 16, g * acc[m][n][r]);
        }
      }
  } else {
    u16* op = Out + (size_t)e * CAP * HDIM;
    const int colb = nt * 256 + wn * 64 + lrow;
    #pragma unroll
    for (int m = 0; m < 8; ++m)
      #pragma unroll
      for (int n = 0; n < 4; ++n)
        #pragma unroll
        for (int r = 0; r < 4; ++r){
          size_t row = (size_t)(rowb + m * 16 + r);
          op[row * HDIM + colb + n * 16] = f2b(acc[m][n][r]);
        }
  }
}

extern "C" void kernel_launch(void* const* d_in, const int* in_sizes, int n_in,
                              void* d_out, int out_size, void* d_ws, size_t ws_size,
                              hipStream_t stream){
  (void)in_sizes; (void)n_in; (void)ws_size;
  const float* x     = (const float*)d_in[0];   // [8192][1024]
  const float* Wg    = (const float*)d_in[1];   // [1024][8]
  const float* W_in  = (const float*)d_in[2];   // [8][1024][4096]
  const float* W_out = (const float*)d_in[3];   // [8][2048][1024]
  float* y = (float*)d_out;

  // workspace layout (~227 MB)
  char* ws = (char*)d_ws;
  u16* WiT   = (u16*)(ws);                       // [8][4096][1024] bf16 (GLU-reordered rows)
  u16* WoT   = (u16*)(ws + 67108864);            // [8][1024][2048] bf16
  u16* Ainp  = (u16*)(ws + 100663296);           // [8][2560][1024] bf16
  u16* hid   = (u16*)(ws + 142606336);           // [8][2560][2048] bf16
  int*   eidx  = (int*)  (ws + 226492416);
  float* vals  = (float*)(ws + 226492416 + 65536);
  int*   slot  = (int*)  (ws + 226492416 + 131072);
  float* gates = (float*)(ws + 226492416 + 196608);
  int*   cnt   = (int*)  (ws + 226492416 + 262144);
  int*   rev   = (int*)  (ws + 226492416 + 266240);   // [8][2560] int

  hipMemsetAsync(y, 0, (size_t)out_size * sizeof(float), stream);
  k_transpose<1><<<dim3(128, 32, 8), dim3(32, 8), 0, stream>>>(W_in,  WiT, 1024, 4096);
  k_transpose<0><<<dim3(32, 64, 8),  dim3(32, 8), 0, stream>>>(W_out, WoT, 2048, 1024);
  k_gating   <<<dim3(2048), dim3(256),  0, stream>>>(x, Wg, eidx, vals);
  k_scan     <<<dim3(1),    dim3(1024), 0, stream>>>(eidx, vals, slot, gates, cnt, rev);
  k_scatter  <<<dim3(2 * S_TOK), dim3(256), 0, stream>>>(x, slot, Ainp);
  // GEMM1: [2560x1024] @ [4096x1024]^T -> GLU -> hid [2560x2048], per expert
  k_gemm8<16, 1024, 4096, 1, 0><<<dim3(10, 16, 8), dim3(512), 0, stream>>>(Ainp, WiT, hid, y, cnt, rev, gates);
  // GEMM2: [2560x2048] @ [1024x2048]^T -> y (fused weighted gather via atomics)
  k_gemm8<32, 2048, 1024, 0, 1><<<dim3(10, 4, 8),  dim3(512), 0, stream>>>(hid, WoT, (u16*)nullptr, y, cnt, rev, gates);
}

// Round 5
// 616.580 us; speedup vs baseline: 1.0895x; 1.0895x over previous
//
#include <hip/hip_runtime.h>
#include <hip/hip_bf16.h>
#include <math.h>

// FlexBertGLUMoE: S=8192 tokens, H=1024, E=8, K=2, F=2048, C=2560
#define S_TOK 8192
#define HDIM  1024
#define FDIM  2048
#define CAP   2560

typedef unsigned short u16;
typedef short  s16x8 __attribute__((ext_vector_type(8)));   // 8 bf16 in 4 VGPRs
typedef float  f32x4 __attribute__((ext_vector_type(4)));

__device__ __forceinline__ u16 f2b(float f){
  unsigned u = __builtin_bit_cast(unsigned, f);
  u = (u + 0x7FFFu + ((u >> 16) & 1u)) >> 16;   // RNE
  return (u16)u;
}
__device__ __forceinline__ float b2f(u16 h){
  unsigned u = ((unsigned)h) << 16;
  return __builtin_bit_cast(float, u);
}
__device__ __forceinline__ void gl_lds16(const u16* g, u16* l){
  // async global->LDS, 16B per lane; LDS dest = wave-uniform base + lane*16
  auto gp = (const __attribute__((address_space(1))) unsigned int*)g;
  auto lp = (__attribute__((address_space(3))) unsigned int*)l;
  __builtin_amdgcn_global_load_lds(gp, lp, 16, 0, 0);
}
// tanh-GELU: max |delta| vs exact erf-GELU ~3e-4, invisible under bf16 rounding
__device__ __forceinline__ float gelu_t(float a){
  float z = 0.7978845608f * a * (1.f + 0.044715f * a * a);
  float e = __expf(-2.f * fabsf(z));
  float th = (1.f - e) / (1.f + e);
  th = (z < 0.f) ? -th : th;
  return 0.5f * a * (1.f + th);
}

// GLU column reorder: W_in col c (0..4095) -> WiT row. Blocks of 64 rows =
// [32 a-cols | 32 g-cols] so each GEMM1 wave owns matching a/g fragments.
__device__ __forceinline__ int glu_reorder(int c){
  int h = (c >= 2048) ? 1 : 0;
  int cc = c - (h << 11);
  return ((cc >> 5) << 6) + (h << 5) + (cc & 31);
}

// ---------------- weight transpose + bf16 cast: [E][R][C] f32 -> [E][C][R] bf16
// 64x64 tiles, float4 loads, ushort4 stores.
template<int REORDER>
__global__ __launch_bounds__(256) void k_transpose(const float* __restrict__ in,
                                                   u16* __restrict__ out, int R, int Cc){
  __shared__ float tl[64][65];
  int e = blockIdx.z;
  const float* ip = in + (size_t)e * R * Cc;
  u16* op = out + (size_t)e * R * Cc;
  int c0 = blockIdx.x * 64, r0 = blockIdx.y * 64;
  int t = threadIdx.x;
  int tx = t & 15, ty = t >> 4;
  #pragma unroll
  for (int p = 0; p < 4; p++){
    int r = ty + p * 16;
    float4 v = *(const float4*)&ip[(size_t)(r0 + r) * Cc + c0 + tx * 4];
    tl[r][tx * 4 + 0] = v.x; tl[r][tx * 4 + 1] = v.y;
    tl[r][tx * 4 + 2] = v.z; tl[r][tx * 4 + 3] = v.w;
  }
  __syncthreads();
  #pragma unroll
  for (int p = 0; p < 4; p++){
    int cc = ty + p * 16;
    int c = c0 + cc;
    int rp = REORDER ? glu_reorder(c) : c;
    int rr = tx * 4;
    ushort4 o;
    o.x = f2b(tl[rr + 0][cc]); o.y = f2b(tl[rr + 1][cc]);
    o.z = f2b(tl[rr + 2][cc]); o.w = f2b(tl[rr + 3][cc]);
    *(ushort4*)&op[(size_t)rp * R + r0 + rr] = o;
  }
}

// ---------------- gating: fp64 logits (ranking must match np ref), softmax, top-2
// LDS-free: Wg rows read directly (L1/L2-resident, 32 KB total).
__global__ __launch_bounds__(256) void k_gating(const float* __restrict__ x,
                                                const float* __restrict__ Wg,
                                                int* __restrict__ eidx, float* __restrict__ vals){
  int t = threadIdx.x, wid = t >> 6, l = t & 63;
  int s = blockIdx.x * 4 + wid;
  const float4* xr = (const float4*)(x + (size_t)s * HDIM);
  const float4* wg = (const float4*)Wg;
  double acc[8] = {0,0,0,0,0,0,0,0};
  #pragma unroll
  for (int j4 = 0; j4 < 4; j4++){
    float4 xv = xr[l * 4 + j4];
    float xa[4] = {xv.x, xv.y, xv.z, xv.w};
    #pragma unroll
    for (int q = 0; q < 4; q++){
      int h = l * 16 + j4 * 4 + q;
      float4 w0 = wg[h * 2], w1 = wg[h * 2 + 1];
      double xd = (double)xa[q];
      acc[0] += xd * w0.x; acc[1] += xd * w0.y; acc[2] += xd * w0.z; acc[3] += xd * w0.w;
      acc[4] += xd * w1.x; acc[5] += xd * w1.y; acc[6] += xd * w1.z; acc[7] += xd * w1.w;
    }
  }
  #pragma unroll
  for (int off = 32; off; off >>= 1)
    #pragma unroll
    for (int e = 0; e < 8; e++) acc[e] += __shfl_down(acc[e], off);
  if (l == 0){
    double mx = acc[0];
    #pragma unroll
    for (int e = 1; e < 8; e++) mx = acc[e] > mx ? acc[e] : mx;
    double ex[8], sum = 0.0;
    #pragma unroll
    for (int e = 0; e < 8; e++){ ex[e] = exp(acc[e] - mx); sum += ex[e]; }
    double inv = 1.0 / sum;
    double p0 = -1.0; int e0 = 0;
    #pragma unroll
    for (int e = 0; e < 8; e++){ double p = ex[e] * inv; if (p > p0){ p0 = p; e0 = e; } }
    double p1 = -1.0; int e1 = 0;
    #pragma unroll
    for (int e = 0; e < 8; e++){ double p = ex[e] * inv; if (e != e0 && p > p1){ p1 = p; e1 = e; } }
    eidx[s] = e0;          vals[s] = (float)p0;
    eidx[S_TOK + s] = e1;  vals[S_TOK + s] = (float)p1;
  }
}

// ---------------- capacity scan (flat order i = k*S + s), slots, gates, counts
// shfl-based wave scan, 2 syncthreads total.
__global__ __launch_bounds__(1024) void k_scan(const int* __restrict__ eidx,
                                               const float* __restrict__ vals,
                                               int* __restrict__ slot, float* __restrict__ gates,
                                               int* __restrict__ cnt){
  __shared__ int wavetot[16][9];
  __shared__ int waveoff[16][9];
  __shared__ unsigned char keepb[2 * S_TOK];
  int t = threadIdx.x, w = t >> 6, l = t & 63;
  int le[16];
  int c[8] = {0,0,0,0,0,0,0,0};
  #pragma unroll
  for (int j = 0; j < 16; j++){ int e = eidx[t * 16 + j]; le[j] = e; c[e]++; }
  int inc[8];
  #pragma unroll
  for (int e = 0; e < 8; e++) inc[e] = c[e];
  #pragma unroll
  for (int off = 1; off < 64; off <<= 1)
    #pragma unroll
    for (int e = 0; e < 8; e++){
      int v = __shfl_up(inc[e], off);
      if (l >= off) inc[e] += v;
    }
  if (l == 63)
    #pragma unroll
    for (int e = 0; e < 8; e++) wavetot[w][e] = inc[e];
  __syncthreads();
  if (t < 8){
    int run = 0;
    for (int ww = 0; ww < 16; ww++){ waveoff[ww][t] = run; run += wavetot[ww][t]; }
    cnt[t] = min(run, CAP);
  }
  __syncthreads();
  int run[8];
  #pragma unroll
  for (int e = 0; e < 8; e++) run[e] = waveoff[w][e] + (inc[e] - c[e]);
  #pragma unroll
  for (int j = 0; j < 16; j++){
    int i = t * 16 + j; int e = le[j]; int loc = run[e]++;
    int kp = (loc < CAP);
    keepb[i] = (unsigned char)kp;
    slot[i] = kp ? (e * CAP + loc) : -1;
  }
  __syncthreads();
  #pragma unroll
  for (int r = 0; r < 8; r++){
    int s = t + 1024 * r;
    float g0 = keepb[s]         ? vals[s]         : 0.f;
    float g1 = keepb[S_TOK + s] ? vals[S_TOK + s] : 0.f;
    float inv = 1.f / fmaxf(g0 + g1, 1e-9f);
    gates[s] = g0 * inv;
    gates[S_TOK + s] = g1 * inv;
  }
}

// ---------------- scatter kept tokens into expert buffers (f32 -> bf16)
__global__ __launch_bounds__(256) void k_scatter(const float* __restrict__ x,
                                                 const int* __restrict__ slot,
                                                 u16* __restrict__ A){
  int i = blockIdx.x;
  int sl = slot[i];
  if (sl < 0) return;
  int s = i & (S_TOK - 1);
  int t = threadIdx.x;
  float4 v = ((const float4*)(x + (size_t)s * HDIM))[t];
  ushort4 o; o.x = f2b(v.x); o.y = f2b(v.y); o.z = f2b(v.z); o.w = f2b(v.w);
  ((ushort4*)(A + (size_t)sl * HDIM))[t] = o;
}

// ================= 256x256 8-phase GEMM (T1+T2+T3+T4+T5) =================
// A [E][CAP][LDK] bf16 row-major, B [E][NB][LDK] bf16 (N-major), BK=64.
// 8 waves as 2M x 4N; per-wave output 128x64. LDS 128KB: A/B x 2 halves x dbuf.
// T2: LDS[row][col] holds global[row][col ^ ((row&7)*8)] (u16 units).
// T1: bijective XCD chunk remap (nwg % 8 == 0).
// R4 change: NO forced lgkmcnt(0)/sched_barrier before MFMA -- compiler emits
// counted lgkm waits and overlaps ds_read latency under the MFMA cluster
// (m141 lesson: order-pinning defeats the scheduler). The only required waits
// are trailing lgkmcnt(0) at phases 3/4 (WAR: drain this wave's LDS reads of a
// region before the barrier that precedes its restaging).

#define STAGE_A(h, tt, par) { \
    const u16* gp_ = Ap + (size_t)((h)*128 + c0*8) * LDK + (size_t)(tt) * 64 + srow_off; \
    u16* lp_ = lds + (par)*16384 + (h)*8192 + c0*512; \
    gl_lds16(gp_, lp_); gl_lds16(gp_ + (size_t)8*LDK, lp_ + 512); }

#define STAGE_B(h, tt, par) { \
    const u16* gp_ = Bp + (size_t)((h)*128 + c0*8) * LDK + (size_t)(tt) * 64 + srow_off; \
    u16* lp_ = lds + 32768 + (par)*16384 + (h)*8192 + c0*512; \
    gl_lds16(gp_, lp_); gl_lds16(gp_ + (size_t)8*LDK, lp_ + 512); }

#define CFENCE asm volatile("" ::: "memory");

#define PH(P, KSW, NH, STAGE_CODE, TAILWAIT, POST_CODE) { \
    if ((NH) == 0) { \
      _Pragma("unroll") \
      for (int m_ = 0; m_ < 8; ++m_) \
        af[m_] = *(const s16x8*)&lds[(P)*16384 + aoff + m_*1024 + (KSW)]; \
    } \
    bf[0] = *(const s16x8*)&lds[32768 + (P)*16384 + boff + (2*(NH))*1024 + (KSW)]; \
    bf[1] = *(const s16x8*)&lds[32768 + (P)*16384 + boff + (2*(NH)+1)*1024 + (KSW)]; \
    STAGE_CODE \
    CFENCE __builtin_amdgcn_s_barrier(); CFENCE \
    __builtin_amdgcn_s_setprio(1); \
    _Pragma("unroll") \
    for (int m_ = 0; m_ < 8; ++m_){ \
      acc[m_][2*(NH)]   = __builtin_amdgcn_mfma_f32_16x16x32_bf16(af[m_], bf[0], acc[m_][2*(NH)],   0, 0, 0); \
      acc[m_][2*(NH)+1] = __builtin_amdgcn_mfma_f32_16x16x32_bf16(af[m_], bf[1], acc[m_][2*(NH)+1], 0, 0, 0); \
    } \
    __builtin_amdgcn_s_setprio(0); \
    if (TAILWAIT){ asm volatile("s_waitcnt lgkmcnt(0)" ::: "memory"); } \
    POST_CODE \
    CFENCE __builtin_amdgcn_s_barrier(); CFENCE }

template<int NK, int LDK, int NB, int IS_GLU>
__global__ __launch_bounds__(512, 2) void k_gemm8(const u16* __restrict__ Aall,
                                                  const u16* __restrict__ Ball,
                                                  u16* __restrict__ Out,
                                                  const int* __restrict__ cnt){
  // T1: bijective chunked XCD remap of the flattened block id (nwg % 8 == 0)
  const int gx = gridDim.x, gy = gridDim.y;
  const int o = blockIdx.x + gx * (blockIdx.y + gy * blockIdx.z);
  const int nwg = gx * gy * (int)gridDim.z;
  const int q = nwg >> 3;
  const int w = (o & 7) * q + (o >> 3);
  const int mt = w % gx;
  const int t1 = w / gx;
  const int nt = t1 % gy;
  const int e  = t1 / gy;
  if (mt * 256 >= cnt[e]) return;
  __shared__ __align__(1024) u16 lds[65536];   // 128 KiB
  const u16* Ap = Aall + (size_t)e * CAP * LDK + (size_t)mt * 256 * LDK;
  const u16* Bp = Ball + (size_t)e * NB * LDK + (size_t)nt * 256 * LDK;

  const int t = threadIdx.x, wid = t >> 6, l = t & 63;
  const int wm = wid >> 2, wn = wid & 3;
  const int lrow = l & 15, lkhi = l >> 4;
  const int c0 = wid * 2;                      // this wave's 2 staging chunks
  const size_t srow_off = (size_t)(l >> 3) * LDK + (size_t)(((l & 7) * 8) ^ ((l >> 3) * 8));
  const int aoff = wm * 8192 + lrow * 64;
  const int boff = (wn >> 1) * 8192 + ((wn & 1) * 64 + lrow) * 64;
  const int sx   = (l & 7) * 8;
  const int ksw0 = (lkhi * 8) ^ sx;
  const int ksw1 = (32 + lkhi * 8) ^ sx;

  f32x4 acc[8][4] = {};
  s16x8 af[8], bf[2];

  // prologue: tile0 (A0,A1,B0,B1 -> buf0), tile1 A-halves -> buf1
  STAGE_A(0, 0, 0) STAGE_A(1, 0, 0) STAGE_B(0, 0, 0) STAGE_B(1, 0, 0)
  STAGE_A(0, 1, 1) STAGE_A(1, 1, 1)
  asm volatile("s_waitcnt vmcnt(4)" ::: "memory");
  CFENCE __builtin_amdgcn_s_barrier(); CFENCE

  #pragma unroll 1
  for (int t2 = 0; t2 < NK / 2; ++t2){
    const int te = 2 * t2;
    const bool nl = (t2 < NK / 2 - 1);
    // ---- tile te (buf 0) ----
    PH(0, ksw0, 0, { STAGE_B(0, te + 1, 1) }, 0, {})
    PH(0, ksw0, 1, { STAGE_B(1, te + 1, 1) }, 0, {})
    PH(0, ksw1, 0, {}, 1, {})
    PH(0, ksw1, 1,
       { if (nl){ STAGE_A(0, te + 2, 0) STAGE_A(1, te + 2, 0) } },
       1,
       { if (nl){ asm volatile("s_waitcnt vmcnt(4)" ::: "memory"); }
         else   { asm volatile("s_waitcnt vmcnt(0)" ::: "memory"); } })
    // ---- tile te+1 (buf 1) ----
    PH(1, ksw0, 0, { if (nl){ STAGE_B(0, te + 2, 0) } }, 0, {})
    PH(1, ksw0, 1, { if (nl){ STAGE_B(1, te + 2, 0) } }, 0, {})
    PH(1, ksw1, 0, {}, 1, {})
    PH(1, ksw1, 1,
       { if (nl){ STAGE_A(0, te + 3, 1) STAGE_A(1, te + 3, 1) } },
       1,
       { if (nl){ asm volatile("s_waitcnt vmcnt(4)" ::: "memory"); } })
  }

  // epilogue
  const int rowb = mt * 256 + wm * 128 + lkhi * 4;
  if (IS_GLU){
    u16* hp = Out + (size_t)e * CAP * FDIM;
    const int colb = (nt * 4 + wn) * 32 + lrow;
    #pragma unroll
    for (int m = 0; m < 8; ++m)
      #pragma unroll
      for (int np = 0; np < 2; ++np)
        #pragma unroll
        for (int r = 0; r < 4; ++r){
          size_t row = (size_t)(rowb + m * 16 + r);
          float a = acc[m][np][r], g = acc[m][np + 2][r];
          hp[row * FDIM + colb + np * 16] = f2b(gelu_t(a) * g);
        }
  } else {
    u16* op = Out + (size_t)e * CAP * HDIM;
    const int colb = nt * 256 + wn * 64 + lrow;
    #pragma unroll
    for (int m = 0; m < 8; ++m)
      #pragma unroll
      for (int n = 0; n < 4; ++n)
        #pragma unroll
        for (int r = 0; r < 4; ++r){
          size_t row = (size_t)(rowb + m * 16 + r);
          op[row * HDIM + colb + n * 16] = f2b(acc[m][n][r]);
        }
  }
}

// ---------------- gather: y[s] = g0*out[slot0] + g1*out[slot1]
__global__ __launch_bounds__(256) void k_gather(const u16* __restrict__ oute,
                                                const int* __restrict__ slot,
                                                const float* __restrict__ gates,
                                                float* __restrict__ y){
  int s = blockIdx.x, t = threadIdx.x;
  int s0 = slot[s], s1 = slot[S_TOK + s];
  float g0 = gates[s], g1 = gates[S_TOK + s];
  float4 r; r.x = r.y = r.z = r.w = 0.f;
  if (s0 >= 0){
    ushort4 v = ((const ushort4*)(oute + (size_t)s0 * HDIM))[t];
    r.x += g0 * b2f(v.x); r.y += g0 * b2f(v.y); r.z += g0 * b2f(v.z); r.w += g0 * b2f(v.w);
  }
  if (s1 >= 0){
    ushort4 v = ((const ushort4*)(oute + (size_t)s1 * HDIM))[t];
    r.x += g1 * b2f(v.x); r.y += g1 * b2f(v.y); r.z += g1 * b2f(v.z); r.w += g1 * b2f(v.w);
  }
  ((float4*)(y + (size_t)s * HDIM))[t] = r;
}

extern "C" void kernel_launch(void* const* d_in, const int* in_sizes, int n_in,
                              void* d_out, int out_size, void* d_ws, size_t ws_size,
                              hipStream_t stream){
  (void)in_sizes; (void)n_in; (void)out_size; (void)ws_size;
  const float* x     = (const float*)d_in[0];   // [8192][1024]
  const float* Wg    = (const float*)d_in[1];   // [1024][8]
  const float* W_in  = (const float*)d_in[2];   // [8][1024][4096]
  const float* W_out = (const float*)d_in[3];   // [8][2048][1024]
  float* y = (float*)d_out;

  // workspace layout (~227 MB)
  char* ws = (char*)d_ws;
  u16* WiT   = (u16*)(ws);                       // [8][4096][1024] bf16 (GLU-reordered rows)
  u16* WoT   = (u16*)(ws + 67108864);            // [8][1024][2048] bf16
  u16* Ainp  = (u16*)(ws + 100663296);           // [8][2560][1024] bf16 (reused as out_e)
  u16* hid   = (u16*)(ws + 142606336);           // [8][2560][2048] bf16
  int*   eidx  = (int*)  (ws + 226492416);
  float* vals  = (float*)(ws + 226492416 + 65536);
  int*   slot  = (int*)  (ws + 226492416 + 131072);
  float* gates = (float*)(ws + 226492416 + 196608);
  int*   cnt   = (int*)  (ws + 226492416 + 262144);

  k_transpose<1><<<dim3(64, 16, 8), dim3(256), 0, stream>>>(W_in,  WiT, 1024, 4096);
  k_transpose<0><<<dim3(16, 32, 8), dim3(256), 0, stream>>>(W_out, WoT, 2048, 1024);
  k_gating   <<<dim3(2048), dim3(256),  0, stream>>>(x, Wg, eidx, vals);
  k_scan     <<<dim3(1),    dim3(1024), 0, stream>>>(eidx, vals, slot, gates, cnt);
  k_scatter  <<<dim3(2 * S_TOK), dim3(256), 0, stream>>>(x, slot, Ainp);
  // GEMM1: [2560x1024] @ [4096x1024]^T -> GLU -> hid [2560x2048], per expert
  k_gemm8<16, 1024, 4096, 1><<<dim3(10, 16, 8), dim3(512), 0, stream>>>(Ainp, WiT, hid, cnt);
  // GEMM2: [2560x2048] @ [1024x2048]^T -> out_e [2560x1024], per expert
  k_gemm8<32, 2048, 1024, 0><<<dim3(10, 4, 8),  dim3(512), 0, stream>>>(hid, WoT, Ainp, cnt);
  k_gather   <<<dim3(S_TOK), dim3(256), 0, stream>>>(Ainp, slot, gates, y);
}